// Round 3
// baseline (303.150 us; speedup 1.0000x reference)
//
#include <hip/hip_runtime.h>
#include <math.h>

// ws layout (float offsets)
#define WS_KV   0        // 300: Wk @ u   (16B aligned)
#define WS_C0   300      // bk . u
#define WS_C1   301      // bq . u2
#define WS_G    304      // 300: g = Wx^3 @ (Wq @ u2)
#define WS_ACC  4096     // 1024*300 partial softmax-weighted sums
#define WS_VSP  311296   // 1024*300 partial v_s sums
#define WS_SCAL 618496   // 1024*2: {denom_partial, mem_len_f}

__device__ __forceinline__ float wred(float v) {
#pragma unroll
    for (int off = 32; off > 0; off >>= 1) v += __shfl_xor(v, off);
    return v;
}

// ---------------------------------------------------------------------------
// k_const: ONE block, 1024 threads. kv = Wk@u, c0 = bk.u, c1 = bq.u2,
// g = Wx(Wx(Wx(Wq@u2))). Wave-per-row coalesced dots + shuffle reduce.
// ---------------------------------------------------------------------------
__global__ __launch_bounds__(1024) void k_const(
    const float* __restrict__ Wx, const float* __restrict__ Wk,
    const float* __restrict__ bk, const float* __restrict__ Wq,
    const float* __restrict__ bq, const float* __restrict__ wmlp,
    float* __restrict__ ws)
{
    const int t = threadIdx.x, wv = t >> 6, lane = t & 63;
    __shared__ float uS[300], u2S[300], hA[300], hB[300];
    if (t < 300) { uS[t] = wmlp[t]; u2S[t] = wmlp[300 + t]; }
    __syncthreads();

    for (int j = wv; j < 300; j += 16) {
        float pk = 0.f, pq = 0.f;
#pragma unroll
        for (int m = 0; m < 5; ++m) {
            int idx = lane + 64 * m;
            if (idx < 300) {
                pk += Wk[j * 300 + idx] * uS[idx];
                pq += Wq[j * 300 + idx] * u2S[idx];
            }
        }
        pk = wred(pk); pq = wred(pq);
        if (lane == 0) { ws[WS_KV + j] = pk; hA[j] = pq; }
    }
    if (wv == 0) {
        float p = 0.f;
#pragma unroll
        for (int m = 0; m < 5; ++m) { int idx = lane + 64 * m; if (idx < 300) p += bk[idx] * uS[idx]; }
        p = wred(p);
        if (lane == 0) ws[WS_C0] = p;
    }
    if (wv == 1) {
        float p = 0.f;
#pragma unroll
        for (int m = 0; m < 5; ++m) { int idx = lane + 64 * m; if (idx < 300) p += bq[idx] * u2S[idx]; }
        p = wred(p);
        if (lane == 0) ws[WS_C1] = p;
    }
    __syncthreads();

#pragma unroll
    for (int hop = 0; hop < 3; ++hop) {
        const float* src = (hop & 1) ? hB : hA;
        float* dst = (hop & 1) ? hA : hB;
        for (int j = wv; j < 300; j += 16) {
            float p = 0.f;
#pragma unroll
            for (int m = 0; m < 5; ++m) {
                int idx = lane + 64 * m;
                if (idx < 300) p += Wx[j * 300 + idx] * src[idx];
            }
            p = wred(p);
            if (lane == 0) dst[j] = p;
        }
        __syncthreads();
    }
    if (t < 300) ws[WS_G + t] = hB[t];   // hA->hB->hA->hB after 3 hops
}

// ---------------------------------------------------------------------------
// k_main: grid 1024 x 512. Block (b, quarter) handles 128 tokens of batch b.
// 8 waves x 16 tokens, ILP-2 pairs, single-pass exp-weighted accumulation.
// Writes UNNORMALIZED partials; k_tail merges the 4 quarters.
// ---------------------------------------------------------------------------
__global__ __launch_bounds__(512, 6) void k_main(
    const int* __restrict__ text, const int* __restrict__ aspect,
    const int* __restrict__ left, const float* __restrict__ embed,
    float* __restrict__ ws)
{
    const int bid = blockIdx.x;
    const int b = bid >> 2, quarter = bid & 3;
    const int t = threadIdx.x, wv = t >> 6, lane = t & 63;

    __shared__ int   toksS[128];
    __shared__ int   atoksS[8];
    __shared__ __align__(16) float accW[8 * 300];
    __shared__ __align__(16) float vsW[8 * 300];
    __shared__ float denomW[8], qpart[5], sc[4];
    __shared__ int   cnts[3];

    if (t < 3) cnts[t] = 0;
    __syncthreads();

    // counts over the FULL row (mask is position-based on mem_len)
    const int tk = text[b * 512 + t];
    const bool predm = (tk != 0);
    if ((t >> 7) == quarter) toksS[t & 127] = tk;
    const bool predl = (t < 64) && (left[b * 64 + t] != 0);
    bool preda = false;
    if (t >= 64 && t < 72) {
        int ak = aspect[b * 8 + (t - 64)];
        atoksS[t - 64] = ak;
        preda = (ak != 0);
    }
    {
        unsigned long long m;
        m = __ballot(predm); if (lane == 0 && m) atomicAdd(&cnts[0], __popcll(m));
        m = __ballot(predl); if (lane == 0 && m) atomicAdd(&cnts[1], __popcll(m));
        m = __ballot(preda); if (lane == 0 && m) atomicAdd(&cnts[2], __popcll(m));
    }
    __syncthreads();

    // qscal = (1/asp_len) * sum_t (sum_a emb[atok_a][t]) * g[t]
    if (wv < 5) {
        float val = 0.f;
        if (t < 300) {
            float s = 0.f;
#pragma unroll
            for (int a = 0; a < 8; ++a) s += embed[(size_t)atoksS[a] * 300 + t];
            val = s * ws[WS_G + t];
        }
        val = wred(val);
        if (lane == 0) qpart[wv] = val;
    }
    __syncthreads();
    if (t == 0) {
        float q = (qpart[0] + qpart[1] + qpart[2] + qpart[3] + qpart[4]) / (float)cnts[2];
        sc[0] = (float)cnts[0];
        sc[1] = (float)(cnts[1] - cnts[2]);
        sc[2] = (float)cnts[1];
        sc[3] = q + ws[WS_C0] + ws[WS_C1];
    }
    __syncthreads();
    const float mem_len_f = sc[0], startf = sc[1], endf = sc[2], qb = sc[3];

    const float4* kv4  = (const float4*)(ws + WS_KV);
    const float4* emb4 = (const float4*)embed;   // row = tok*75 float4s
    const bool hasB = (lane < 11);
    const float4 kva = kv4[lane];
    const float4 kvb = hasB ? kv4[64 + lane] : make_float4(0.f, 0.f, 0.f, 0.f);

    float4 accA = make_float4(0.f,0.f,0.f,0.f), accB = make_float4(0.f,0.f,0.f,0.f);
    float4 vsA  = make_float4(0.f,0.f,0.f,0.f), vsB  = make_float4(0.f,0.f,0.f,0.f);
    float denom = 0.f;
    const float posbase = (float)(quarter * 128);

    for (int it = 0; it < 8; ++it) {
        const int l0 = wv * 16 + 2 * it, l1 = l0 + 1;
        const int r0 = toksS[l0] * 75, r1 = toksS[l1] * 75;
        float4 a0 = emb4[r0 + lane];
        float4 a1 = emb4[r1 + lane];
        float4 b0 = hasB ? emb4[r0 + 64 + lane] : make_float4(0.f,0.f,0.f,0.f);
        float4 b1 = hasB ? emb4[r1 + 64 + lane] : make_float4(0.f,0.f,0.f,0.f);

        float pd0 = a0.x*kva.x + a0.y*kva.y + a0.z*kva.z + a0.w*kva.w
                  + b0.x*kvb.x + b0.y*kvb.y + b0.z*kvb.z + b0.w*kvb.w;
        float pd1 = a1.x*kva.x + a1.y*kva.y + a1.z*kva.z + a1.w*kva.w
                  + b1.x*kvb.x + b1.y*kvb.y + b1.z*kvb.z + b1.w*kvb.w;
#pragma unroll
        for (int off = 32; off > 0; off >>= 1) {
            pd0 += __shfl_xor(pd0, off);
            pd1 += __shfl_xor(pd1, off);
        }

        const float f0 = posbase + (float)l0, f1 = f0 + 1.f;
        float lv0 = (f0 < startf) ? (startf - f0) : ((f0 <= endf) ? 0.f : (f0 - endf));
        float lv1 = (f1 < startf) ? (startf - f1) : ((f1 <= endf) ? 0.f : (f1 - endf));
        float w0 = 1.f - lv0 / mem_len_f; w0 = (f0 < mem_len_f) ? w0 : 0.f;
        float w1 = 1.f - lv1 / mem_len_f; w1 = (f1 < mem_len_f) ? w1 : 0.f;

        const float p0 = expf(tanhf(w0 * pd0 + qb));
        const float p1 = expf(tanhf(w1 * pd1 + qb));
        const float pw0 = p0 * w0, pw1 = p1 * w1;

        accA.x += pw0*a0.x + pw1*a1.x;  accA.y += pw0*a0.y + pw1*a1.y;
        accA.z += pw0*a0.z + pw1*a1.z;  accA.w += pw0*a0.w + pw1*a1.w;
        accB.x += pw0*b0.x + pw1*b1.x;  accB.y += pw0*b0.y + pw1*b1.y;
        accB.z += pw0*b0.z + pw1*b1.z;  accB.w += pw0*b0.w + pw1*b1.w;
        vsA.x += a0.x + a1.x;  vsA.y += a0.y + a1.y;
        vsA.z += a0.z + a1.z;  vsA.w += a0.w + a1.w;
        vsB.x += b0.x + b1.x;  vsB.y += b0.y + b1.y;
        vsB.z += b0.z + b1.z;  vsB.w += b0.w + b1.w;
        denom += p0 + p1;
    }

    *(float4*)&accW[wv * 300 + 4 * lane] = accA;
    *(float4*)&vsW [wv * 300 + 4 * lane] = vsA;
    if (hasB) {
        *(float4*)&accW[wv * 300 + 256 + 4 * lane] = accB;
        *(float4*)&vsW [wv * 300 + 256 + 4 * lane] = vsB;
    }
    if (lane == 0) denomW[wv] = denom;
    __syncthreads();

    if (t < 300) {
        float ds = 0.f;
#pragma unroll
        for (int w = 0; w < 8; ++w) ds += denomW[w];
        float ms = 0.f, vs = 0.f;
#pragma unroll
        for (int w = 0; w < 8; ++w) { ms += accW[w * 300 + t]; vs += vsW[w * 300 + t]; }
        ws[WS_ACC + bid * 300 + t] = ms;
        ws[WS_VSP + bid * 300 + t] = vs;
        if (t == 0) { ws[WS_SCAL + bid * 2] = ds; ws[WS_SCAL + bid * 2 + 1] = mem_len_f; }
    }
}

// ---------------------------------------------------------------------------
// k_tail: grid 256 x 960. Merge 4 quarter-partials, then:
// T = mw@Wk + bk ; A = T@Wproj + bproj + v_s ; vms = tanh(A@Wm + bm);
// out = softmax(vms@Wd + bd). 3-way K-split per GEMM.
// ---------------------------------------------------------------------------
__global__ __launch_bounds__(960) void k_tail(
    const float* __restrict__ Wk, const float* __restrict__ bk,
    const float* __restrict__ Wproj, const float* __restrict__ bproj,
    const float* __restrict__ Wm, const float* __restrict__ bm,
    const float* __restrict__ Wd, const float* __restrict__ bd,
    float* __restrict__ out, const float* __restrict__ ws)
{
    const int t = threadIdx.x;
    const int b = blockIdx.x;
    const int seg = t / 320, j = t - seg * 320;

    __shared__ float A[300], T[300], VSs[300], part[900], vms[300], lg[3];

    if (t < 300) {
        const int p0 = (b * 4) * 300 + t;
        float a = ws[WS_ACC + p0] + ws[WS_ACC + p0 + 300]
                + ws[WS_ACC + p0 + 600] + ws[WS_ACC + p0 + 900];
        float v = ws[WS_VSP + p0] + ws[WS_VSP + p0 + 300]
                + ws[WS_VSP + p0 + 600] + ws[WS_VSP + p0 + 900];
        const int s0 = b * 8;
        float d  = ws[WS_SCAL + s0] + ws[WS_SCAL + s0 + 2]
                 + ws[WS_SCAL + s0 + 4] + ws[WS_SCAL + s0 + 6];
        float ml = ws[WS_SCAL + s0 + 1];
        A[t]   = a / d;
        VSs[t] = v / ml;
    }
    __syncthreads();

    // GEMM1: T = A @ Wk + bk
    if (j < 300) {
        const int k0 = seg * 100;
        float acc = 0.f;
#pragma unroll 10
        for (int i = 0; i < 100; ++i) acc += A[k0 + i] * Wk[(k0 + i) * 300 + j];
        part[seg * 300 + j] = acc;
    }
    __syncthreads();
    if (t < 300) T[t] = part[t] + part[300 + t] + part[600 + t] + bk[t];
    __syncthreads();

    // GEMM2: A = T @ Wproj + bproj + v_s
    if (j < 300) {
        const int k0 = seg * 100;
        float acc = 0.f;
#pragma unroll 10
        for (int i = 0; i < 100; ++i) acc += T[k0 + i] * Wproj[(k0 + i) * 300 + j];
        part[seg * 300 + j] = acc;
    }
    __syncthreads();
    if (t < 300) A[t] = part[t] + part[300 + t] + part[600 + t] + bproj[t] + VSs[t];
    __syncthreads();

    // GEMM3: vms = tanh(A @ Wm + bm)
    if (j < 300) {
        const int k0 = seg * 100;
        float acc = 0.f;
#pragma unroll 10
        for (int i = 0; i < 100; ++i) acc += A[k0 + i] * Wm[(k0 + i) * 300 + j];
        part[seg * 300 + j] = acc;
    }
    __syncthreads();
    if (t < 300) vms[t] = tanhf(part[t] + part[300 + t] + part[600 + t] + bm[t]);
    __syncthreads();

    const int wv = t >> 6, lane = t & 63;
    if (wv < 3) {
        float p = 0.f;
#pragma unroll
        for (int k = 0; k < 5; ++k) { int d = lane + 64 * k; if (d < 300) p += vms[d] * Wd[d * 3 + wv]; }
        p = wred(p);
        if (lane == 0) lg[wv] = p + bd[wv];
    }
    __syncthreads();
    if (t == 0) {
        float l0 = lg[0], l1 = lg[1], l2 = lg[2];
        float mx = fmaxf(l0, fmaxf(l1, l2));
        float e0 = expf(l0 - mx), e1 = expf(l1 - mx), e2 = expf(l2 - mx);
        float s = e0 + e1 + e2;
        out[b * 3 + 0] = e0 / s;
        out[b * 3 + 1] = e1 / s;
        out[b * 3 + 2] = e2 / s;
    }
}

extern "C" void kernel_launch(void* const* d_in, const int* in_sizes, int n_in,
                              void* d_out, int out_size, void* d_ws, size_t ws_size,
                              hipStream_t stream)
{
    (void)in_sizes; (void)n_in; (void)out_size; (void)ws_size;
    const int*   text   = (const int*)d_in[0];
    const int*   aspect = (const int*)d_in[1];
    const int*   left   = (const int*)d_in[2];
    const float* embed  = (const float*)d_in[3];
    const float* Wx     = (const float*)d_in[4];
    // d_in[5] = Ws : dead code in reference
    const float* Wk     = (const float*)d_in[6];
    const float* bk     = (const float*)d_in[7];
    const float* Wq     = (const float*)d_in[8];
    const float* bq     = (const float*)d_in[9];
    const float* wmlp   = (const float*)d_in[10];
    const float* Wproj  = (const float*)d_in[11];
    const float* bproj  = (const float*)d_in[12];
    const float* Wm     = (const float*)d_in[13];
    const float* bm     = (const float*)d_in[14];
    const float* Wd     = (const float*)d_in[15];
    const float* bd     = (const float*)d_in[16];
    float* out = (float*)d_out;
    float* ws  = (float*)d_ws;

    hipLaunchKernelGGL(k_const, dim3(1), dim3(1024), 0, stream,
                       Wx, Wk, bk, Wq, bq, wmlp, ws);
    hipLaunchKernelGGL(k_main, dim3(1024), dim3(512), 0, stream,
                       text, aspect, left, embed, ws);
    hipLaunchKernelGGL(k_tail, dim3(256), dim3(960), 0, stream,
                       Wk, bk, Wproj, bproj, Wm, bm, Wd, bd, out, ws);
}

// Round 4
// 294.411 us; speedup vs baseline: 1.0297x; 1.0297x over previous
//
#include <hip/hip_runtime.h>
#include <math.h>

// ws layout (float offsets)
#define WS_KV   0        // 300: Wk @ u   (16B aligned)
#define WS_C0   300      // bk . u
#define WS_C1   301      // bq . u2
#define WS_H0   304      // 300: hop ping
#define WS_H1   640      // 300: hop pong; g = final H1
#define WS_ROW  2048     // 256*4: {mem_len_f, startf, endf, qb}
#define WS_ACC  4096     // 1024*300 partial softmax-weighted sums
#define WS_VSP  311296   // 1024*300 partial v_s sums
#define WS_SCAL 618496   // 1024*2: {denom_partial, mem_len_f}

__device__ __forceinline__ float wred(float v) {
#pragma unroll
    for (int off = 32; off > 0; off >>= 1) v += __shfl_xor(v, off);
    return v;
}

// fast tanh via hardware exp; |err| ~1e-7 relative, way under 6.7e-3 threshold
__device__ __forceinline__ float ftanh(float z) {
    float t = __expf(2.f * z);
    return (t - 1.f) / (t + 1.f);
}

// ---------------------------------------------------------------------------
// k_prep: grid 302 x 64 (grid-parallel — single-block version measured 71us!)
//  blocks 0..299: kv[j] = Wk row j . u ; h0[j] = Wq row j . u2
//  block 300: c0 = bk.u ; block 301: c1 = bq.u2
// ---------------------------------------------------------------------------
__global__ __launch_bounds__(64) void k_prep(
    const float* __restrict__ Wk, const float* __restrict__ bk,
    const float* __restrict__ Wq, const float* __restrict__ bq,
    const float* __restrict__ wmlp, float* __restrict__ ws)
{
    const int lane = threadIdx.x;
    const int j = blockIdx.x;
    const float* u  = wmlp;
    const float* u2 = wmlp + 300;
    if (j < 300) {
        float pk = 0.f, pq = 0.f;
#pragma unroll
        for (int m = 0; m < 5; ++m) {
            int idx = lane + 64 * m;
            if (idx < 300) {
                pk += Wk[j * 300 + idx] * u[idx];
                pq += Wq[j * 300 + idx] * u2[idx];
            }
        }
        pk = wred(pk); pq = wred(pq);
        if (lane == 0) { ws[WS_KV + j] = pk; ws[WS_H0 + j] = pq; }
    } else if (j == 300) {
        float p = 0.f;
#pragma unroll
        for (int m = 0; m < 5; ++m) { int idx = lane + 64 * m; if (idx < 300) p += bk[idx] * u[idx]; }
        p = wred(p);
        if (lane == 0) ws[WS_C0] = p;
    } else {
        float p = 0.f;
#pragma unroll
        for (int m = 0; m < 5; ++m) { int idx = lane + 64 * m; if (idx < 300) p += bq[idx] * u2[idx]; }
        p = wred(p);
        if (lane == 0) ws[WS_C1] = p;
    }
}

// ---------------------------------------------------------------------------
// k_hop: grid 300 x 64: dst[j] = Wx row j . src. Launched 3x (H0->H1->H0->H1).
// ---------------------------------------------------------------------------
__global__ __launch_bounds__(64) void k_hop(
    const float* __restrict__ Wx, const float* __restrict__ src,
    float* __restrict__ dst)
{
    const int lane = threadIdx.x;
    const int j = blockIdx.x;
    float p = 0.f;
#pragma unroll
    for (int m = 0; m < 5; ++m) {
        int idx = lane + 64 * m;
        if (idx < 300) p += Wx[j * 300 + idx] * src[idx];
    }
    p = wred(p);
    if (lane == 0) dst[j] = p;
}

// ---------------------------------------------------------------------------
// k_row: grid 256 x 512. Per-batch-row scalars, computed ONCE (not 4x/row):
//   mem_len, start, end, qb = asp_e.g + c0 + c1
// ---------------------------------------------------------------------------
__global__ __launch_bounds__(512) void k_row(
    const int* __restrict__ text, const int* __restrict__ aspect,
    const int* __restrict__ left, const float* __restrict__ embed,
    float* __restrict__ ws)
{
    const int b = blockIdx.x;
    const int t = threadIdx.x, wv = t >> 6, lane = t & 63;

    __shared__ int   atoks[8];
    __shared__ int   cntW[8];
    __shared__ float qp[5];
    __shared__ int   lCnt, aCnt;

    const int tk = text[b * 512 + t];
    {
        unsigned long long m = __ballot(tk != 0);
        if (lane == 0) cntW[wv] = __popcll(m);
    }
    if (wv == 0) {
        unsigned long long m = __ballot(left[b * 64 + lane] != 0);
        if (lane == 0) lCnt = __popcll(m);
    }
    if (wv == 1) {
        int ak = (lane < 8) ? aspect[b * 8 + lane] : 0;
        if (lane < 8) atoks[lane] = ak;
        unsigned long long m = __ballot(lane < 8 && ak != 0);
        if (lane == 0) aCnt = __popcll(m);
    }
    __syncthreads();

    if (wv < 5) {
        float v = 0.f;
        if (t < 300) {
            float s = 0.f;
#pragma unroll
            for (int a = 0; a < 8; ++a) s += embed[(size_t)atoks[a] * 300 + t];
            v = s * ws[WS_H1 + t];   // g lives in H1 after 3 hops
        }
        v = wred(v);
        if (lane == 0) qp[wv] = v;
    }
    __syncthreads();

    if (t == 0) {
        int ml = 0;
#pragma unroll
        for (int w = 0; w < 8; ++w) ml += cntW[w];
        float q = (qp[0] + qp[1] + qp[2] + qp[3] + qp[4]) / (float)aCnt
                + ws[WS_C0] + ws[WS_C1];
        ws[WS_ROW + b * 4 + 0] = (float)ml;
        ws[WS_ROW + b * 4 + 1] = (float)(lCnt - aCnt);
        ws[WS_ROW + b * 4 + 2] = (float)lCnt;
        ws[WS_ROW + b * 4 + 3] = q;
    }
}

// ---------------------------------------------------------------------------
// k_main: grid 1024 x 512. Block (b, quarter): 128 tokens of batch b.
// 8 waves x 16 tokens, ILP-4 (8 loads in flight, 4 interleaved shuffle
// chains). No per-block counting preamble — scalars come from k_row.
// Writes UNNORMALIZED partials; k_tail merges quarters.
// ---------------------------------------------------------------------------
__global__ __launch_bounds__(512, 4) void k_main(
    const int* __restrict__ text, const float* __restrict__ embed,
    float* __restrict__ ws)
{
    const int bid = blockIdx.x;
    const int b = bid >> 2, quarter = bid & 3;
    const int t = threadIdx.x, wv = t >> 6, lane = t & 63;

    __shared__ int   toksS[128];
    __shared__ __align__(16) float accW[8 * 300];
    __shared__ __align__(16) float vsW[8 * 300];
    __shared__ float denomW[8], sc[4];

    if (t < 128) toksS[t] = text[b * 512 + quarter * 128 + t];
    if (t >= 128 && t < 132) sc[t - 128] = ws[WS_ROW + b * 4 + (t - 128)];
    __syncthreads();
    const float mem_len_f = sc[0], startf = sc[1], endf = sc[2], qb = sc[3];
    const float inv_ml = 1.f / mem_len_f;

    const float4* kv4  = (const float4*)(ws + WS_KV);
    const float4* emb4 = (const float4*)embed;   // row = tok*75 float4s
    const bool hasB = (lane < 11);
    const float4 kva = kv4[lane];
    const float4 kvb = hasB ? kv4[64 + lane] : make_float4(0.f, 0.f, 0.f, 0.f);
    const float4 fz = make_float4(0.f, 0.f, 0.f, 0.f);

    float4 accA = fz, accB = fz, vsA = fz, vsB = fz;
    float denom = 0.f;
    const float posbase = (float)(quarter * 128);

    for (int it = 0; it < 4; ++it) {
        const int base = wv * 16 + 4 * it;
        int rr[4];
#pragma unroll
        for (int k = 0; k < 4; ++k) rr[k] = toksS[base + k] * 75;
        float4 A[4], Bv[4];
#pragma unroll
        for (int k = 0; k < 4; ++k) A[k] = emb4[rr[k] + lane];
#pragma unroll
        for (int k = 0; k < 4; ++k) Bv[k] = hasB ? emb4[rr[k] + 64 + lane] : fz;

        float pd[4];
#pragma unroll
        for (int k = 0; k < 4; ++k)
            pd[k] = A[k].x*kva.x + A[k].y*kva.y + A[k].z*kva.z + A[k].w*kva.w
                  + Bv[k].x*kvb.x + Bv[k].y*kvb.y + Bv[k].z*kvb.z + Bv[k].w*kvb.w;
#pragma unroll
        for (int off = 32; off > 0; off >>= 1) {
#pragma unroll
            for (int k = 0; k < 4; ++k) pd[k] += __shfl_xor(pd[k], off);
        }

#pragma unroll
        for (int k = 0; k < 4; ++k) {
            const float f = posbase + (float)(base + k);
            float lv = (f < startf) ? (startf - f) : ((f <= endf) ? 0.f : (f - endf));
            float wgt = 1.f - lv * inv_ml;
            wgt = (f < mem_len_f) ? wgt : 0.f;
            const float p = __expf(ftanh(wgt * pd[k] + qb));
            const float pw = p * wgt;
            accA.x += pw * A[k].x;  accA.y += pw * A[k].y;
            accA.z += pw * A[k].z;  accA.w += pw * A[k].w;
            accB.x += pw * Bv[k].x; accB.y += pw * Bv[k].y;
            accB.z += pw * Bv[k].z; accB.w += pw * Bv[k].w;
            vsA.x += A[k].x;  vsA.y += A[k].y;  vsA.z += A[k].z;  vsA.w += A[k].w;
            vsB.x += Bv[k].x; vsB.y += Bv[k].y; vsB.z += Bv[k].z; vsB.w += Bv[k].w;
            denom += p;
        }
    }

    *(float4*)&accW[wv * 300 + 4 * lane] = accA;
    *(float4*)&vsW [wv * 300 + 4 * lane] = vsA;
    if (hasB) {
        *(float4*)&accW[wv * 300 + 256 + 4 * lane] = accB;
        *(float4*)&vsW [wv * 300 + 256 + 4 * lane] = vsB;
    }
    if (lane == 0) denomW[wv] = denom;
    __syncthreads();

    if (t < 300) {
        float ds = 0.f;
#pragma unroll
        for (int w = 0; w < 8; ++w) ds += denomW[w];
        float ms = 0.f, vs = 0.f;
#pragma unroll
        for (int w = 0; w < 8; ++w) { ms += accW[w * 300 + t]; vs += vsW[w * 300 + t]; }
        ws[WS_ACC + bid * 300 + t] = ms;
        ws[WS_VSP + bid * 300 + t] = vs;
        if (t == 0) { ws[WS_SCAL + bid * 2] = ds; ws[WS_SCAL + bid * 2 + 1] = mem_len_f; }
    }
}

// ---------------------------------------------------------------------------
// k_tail: grid 256 x 960. Merge 4 quarter-partials, then 3 chained GEMVs
// (3-way K-split) + logits + softmax.
// ---------------------------------------------------------------------------
__global__ __launch_bounds__(960) void k_tail(
    const float* __restrict__ Wk, const float* __restrict__ bk,
    const float* __restrict__ Wproj, const float* __restrict__ bproj,
    const float* __restrict__ Wm, const float* __restrict__ bm,
    const float* __restrict__ Wd, const float* __restrict__ bd,
    float* __restrict__ out, const float* __restrict__ ws)
{
    const int t = threadIdx.x;
    const int b = blockIdx.x;
    const int seg = t / 320, j = t - seg * 320;

    __shared__ float A[300], T[300], VSs[300], part[900], vms[300], lg[3];

    if (t < 300) {
        const int p0 = (b * 4) * 300 + t;
        float a = ws[WS_ACC + p0] + ws[WS_ACC + p0 + 300]
                + ws[WS_ACC + p0 + 600] + ws[WS_ACC + p0 + 900];
        float v = ws[WS_VSP + p0] + ws[WS_VSP + p0 + 300]
                + ws[WS_VSP + p0 + 600] + ws[WS_VSP + p0 + 900];
        const int s0 = b * 8;
        float d  = ws[WS_SCAL + s0] + ws[WS_SCAL + s0 + 2]
                 + ws[WS_SCAL + s0 + 4] + ws[WS_SCAL + s0 + 6];
        float ml = ws[WS_SCAL + s0 + 1];
        A[t]   = a / d;
        VSs[t] = v / ml;
    }
    __syncthreads();

    if (j < 300) {
        const int k0 = seg * 100;
        float acc = 0.f;
#pragma unroll 10
        for (int i = 0; i < 100; ++i) acc += A[k0 + i] * Wk[(k0 + i) * 300 + j];
        part[seg * 300 + j] = acc;
    }
    __syncthreads();
    if (t < 300) T[t] = part[t] + part[300 + t] + part[600 + t] + bk[t];
    __syncthreads();

    if (j < 300) {
        const int k0 = seg * 100;
        float acc = 0.f;
#pragma unroll 10
        for (int i = 0; i < 100; ++i) acc += T[k0 + i] * Wproj[(k0 + i) * 300 + j];
        part[seg * 300 + j] = acc;
    }
    __syncthreads();
    if (t < 300) A[t] = part[t] + part[300 + t] + part[600 + t] + bproj[t] + VSs[t];
    __syncthreads();

    if (j < 300) {
        const int k0 = seg * 100;
        float acc = 0.f;
#pragma unroll 10
        for (int i = 0; i < 100; ++i) acc += A[k0 + i] * Wm[(k0 + i) * 300 + j];
        part[seg * 300 + j] = acc;
    }
    __syncthreads();
    if (t < 300) vms[t] = tanhf(part[t] + part[300 + t] + part[600 + t] + bm[t]);
    __syncthreads();

    const int wv = t >> 6, lane = t & 63;
    if (wv < 3) {
        float p = 0.f;
#pragma unroll
        for (int k = 0; k < 5; ++k) { int d = lane + 64 * k; if (d < 300) p += vms[d] * Wd[d * 3 + wv]; }
        p = wred(p);
        if (lane == 0) lg[wv] = p + bd[wv];
    }
    __syncthreads();
    if (t == 0) {
        float l0 = lg[0], l1 = lg[1], l2 = lg[2];
        float mx = fmaxf(l0, fmaxf(l1, l2));
        float e0 = expf(l0 - mx), e1 = expf(l1 - mx), e2 = expf(l2 - mx);
        float s = e0 + e1 + e2;
        out[b * 3 + 0] = e0 / s;
        out[b * 3 + 1] = e1 / s;
        out[b * 3 + 2] = e2 / s;
    }
}

extern "C" void kernel_launch(void* const* d_in, const int* in_sizes, int n_in,
                              void* d_out, int out_size, void* d_ws, size_t ws_size,
                              hipStream_t stream)
{
    (void)in_sizes; (void)n_in; (void)out_size; (void)ws_size;
    const int*   text   = (const int*)d_in[0];
    const int*   aspect = (const int*)d_in[1];
    const int*   left   = (const int*)d_in[2];
    const float* embed  = (const float*)d_in[3];
    const float* Wx     = (const float*)d_in[4];
    // d_in[5] = Ws : dead code in reference
    const float* Wk     = (const float*)d_in[6];
    const float* bk     = (const float*)d_in[7];
    const float* Wq     = (const float*)d_in[8];
    const float* bq     = (const float*)d_in[9];
    const float* wmlp   = (const float*)d_in[10];
    const float* Wproj  = (const float*)d_in[11];
    const float* bproj  = (const float*)d_in[12];
    const float* Wm     = (const float*)d_in[13];
    const float* bm     = (const float*)d_in[14];
    const float* Wd     = (const float*)d_in[15];
    const float* bd     = (const float*)d_in[16];
    float* out = (float*)d_out;
    float* ws  = (float*)d_ws;

    hipLaunchKernelGGL(k_prep, dim3(302), dim3(64), 0, stream, Wk, bk, Wq, bq, wmlp, ws);
    hipLaunchKernelGGL(k_hop, dim3(300), dim3(64), 0, stream, Wx, ws + WS_H0, ws + WS_H1);
    hipLaunchKernelGGL(k_hop, dim3(300), dim3(64), 0, stream, Wx, ws + WS_H1, ws + WS_H0);
    hipLaunchKernelGGL(k_hop, dim3(300), dim3(64), 0, stream, Wx, ws + WS_H0, ws + WS_H1);
    hipLaunchKernelGGL(k_row, dim3(256), dim3(512), 0, stream, text, aspect, left, embed, ws);
    hipLaunchKernelGGL(k_main, dim3(1024), dim3(512), 0, stream, text, embed, ws);
    hipLaunchKernelGGL(k_tail, dim3(256), dim3(960), 0, stream,
                       Wk, bk, Wproj, bproj, Wm, bm, Wd, bd, out, ws);
}

// Round 5
// 256.386 us; speedup vs baseline: 1.1824x; 1.1483x over previous
//
#include <hip/hip_runtime.h>
#include <math.h>

// ws layout (float offsets)
#define WS_KV   0        // 300: Wk @ u   (16B aligned)
#define WS_C0   300      // bk . u
#define WS_C1   301      // bq . u2
#define WS_H0   304      // 300: hop ping
#define WS_H1   640      // 300: hop pong; g = final H1
#define WS_ROW  2048     // 256*4: {mem_len_f, startf, endf, qb}
#define WS_ACC  4096     // 1024*300 partial softmax-weighted sums
#define WS_VSP  311296   // 1024*300 partial v_s sums
#define WS_SCAL 618496   // 1024*2: {denom_partial, mem_len_f}

__device__ __forceinline__ float wred(float v) {
#pragma unroll
    for (int off = 32; off > 0; off >>= 1) v += __shfl_xor(v, off);
    return v;
}

// fast tanh via hardware exp; error way under the 6.7e-3 threshold
__device__ __forceinline__ float ftanh(float z) {
    float t = __expf(2.f * z);
    return (t - 1.f) / (t + 1.f);
}

// ---------------------------------------------------------------------------
// k_prep: grid 302 x 64 (grid-parallel; single-block fusion measured 71us)
// ---------------------------------------------------------------------------
__global__ __launch_bounds__(64) void k_prep(
    const float* __restrict__ Wk, const float* __restrict__ bk,
    const float* __restrict__ Wq, const float* __restrict__ bq,
    const float* __restrict__ wmlp, float* __restrict__ ws)
{
    const int lane = threadIdx.x;
    const int j = blockIdx.x;
    const float* u  = wmlp;
    const float* u2 = wmlp + 300;
    if (j < 300) {
        float pk = 0.f, pq = 0.f;
#pragma unroll
        for (int m = 0; m < 5; ++m) {
            int idx = lane + 64 * m;
            if (idx < 300) {
                pk += Wk[j * 300 + idx] * u[idx];
                pq += Wq[j * 300 + idx] * u2[idx];
            }
        }
        pk = wred(pk); pq = wred(pq);
        if (lane == 0) { ws[WS_KV + j] = pk; ws[WS_H0 + j] = pq; }
    } else if (j == 300) {
        float p = 0.f;
#pragma unroll
        for (int m = 0; m < 5; ++m) { int idx = lane + 64 * m; if (idx < 300) p += bk[idx] * u[idx]; }
        p = wred(p);
        if (lane == 0) ws[WS_C0] = p;
    } else {
        float p = 0.f;
#pragma unroll
        for (int m = 0; m < 5; ++m) { int idx = lane + 64 * m; if (idx < 300) p += bq[idx] * u2[idx]; }
        p = wred(p);
        if (lane == 0) ws[WS_C1] = p;
    }
}

// ---------------------------------------------------------------------------
// k_hop: grid 300 x 64: dst[j] = Wx row j . src. Launched 3x.
// ---------------------------------------------------------------------------
__global__ __launch_bounds__(64) void k_hop(
    const float* __restrict__ Wx, const float* __restrict__ src,
    float* __restrict__ dst)
{
    const int lane = threadIdx.x;
    const int j = blockIdx.x;
    float p = 0.f;
#pragma unroll
    for (int m = 0; m < 5; ++m) {
        int idx = lane + 64 * m;
        if (idx < 300) p += Wx[j * 300 + idx] * src[idx];
    }
    p = wred(p);
    if (lane == 0) dst[j] = p;
}

// ---------------------------------------------------------------------------
// k_row: grid 256 x 512. Per-batch-row scalars, once per row.
// ---------------------------------------------------------------------------
__global__ __launch_bounds__(512) void k_row(
    const int* __restrict__ text, const int* __restrict__ aspect,
    const int* __restrict__ left, const float* __restrict__ embed,
    float* __restrict__ ws)
{
    const int b = blockIdx.x;
    const int t = threadIdx.x, wv = t >> 6, lane = t & 63;

    __shared__ int   atoks[8];
    __shared__ int   cntW[8];
    __shared__ float qp[5];
    __shared__ int   lCnt, aCnt;

    const int tk = text[b * 512 + t];
    {
        unsigned long long m = __ballot(tk != 0);
        if (lane == 0) cntW[wv] = __popcll(m);
    }
    if (wv == 0) {
        unsigned long long m = __ballot(left[b * 64 + lane] != 0);
        if (lane == 0) lCnt = __popcll(m);
    }
    if (wv == 1) {
        int ak = (lane < 8) ? aspect[b * 8 + lane] : 0;
        if (lane < 8) atoks[lane] = ak;
        unsigned long long m = __ballot(lane < 8 && ak != 0);
        if (lane == 0) aCnt = __popcll(m);
    }
    __syncthreads();

    if (wv < 5) {
        float v = 0.f;
        if (t < 300) {
            float s = 0.f;
#pragma unroll
            for (int a = 0; a < 8; ++a) s += embed[(size_t)atoks[a] * 300 + t];
            v = s * ws[WS_H1 + t];   // g lives in H1 after 3 hops
        }
        v = wred(v);
        if (lane == 0) qp[wv] = v;
    }
    __syncthreads();

    if (t == 0) {
        int ml = 0;
#pragma unroll
        for (int w = 0; w < 8; ++w) ml += cntW[w];
        float q = (qp[0] + qp[1] + qp[2] + qp[3] + qp[4]) / (float)aCnt
                + ws[WS_C0] + ws[WS_C1];
        ws[WS_ROW + b * 4 + 0] = (float)ml;
        ws[WS_ROW + b * 4 + 1] = (float)(lCnt - aCnt);
        ws[WS_ROW + b * 4 + 2] = (float)lCnt;
        ws[WS_ROW + b * 4 + 3] = q;
    }
}

// ---------------------------------------------------------------------------
// k_main: grid 1024 x 512. Block (b, quarter): 128 tokens of batch b.
// launch_bounds(512, 2): 2 blocks/CU -> 128-VGPR cap (loop needs ~85).
// (512,4) forced 64 VGPRs -> scratch spills: 121 MB WRITE_SIZE, 94us. DO NOT.
// ---------------------------------------------------------------------------
__global__ __launch_bounds__(512, 2) void k_main(
    const int* __restrict__ text, const float* __restrict__ embed,
    float* __restrict__ ws)
{
    const int bid = blockIdx.x;
    const int b = bid >> 2, quarter = bid & 3;
    const int t = threadIdx.x, wv = t >> 6, lane = t & 63;

    __shared__ int   toksS[128];
    __shared__ __align__(16) float accW[8 * 300];
    __shared__ __align__(16) float vsW[8 * 300];
    __shared__ float denomW[8], sc[4];

    if (t < 128) toksS[t] = text[b * 512 + quarter * 128 + t];
    if (t >= 128 && t < 132) sc[t - 128] = ws[WS_ROW + b * 4 + (t - 128)];
    __syncthreads();
    const float mem_len_f = sc[0], startf = sc[1], endf = sc[2], qb = sc[3];
    const float inv_ml = 1.f / mem_len_f;

    const float4* kv4  = (const float4*)(ws + WS_KV);
    const float4* emb4 = (const float4*)embed;   // row = tok*75 float4s
    const bool hasB = (lane < 11);
    const float4 kva = kv4[lane];
    const float4 kvb = hasB ? kv4[64 + lane] : make_float4(0.f, 0.f, 0.f, 0.f);
    const float4 fz = make_float4(0.f, 0.f, 0.f, 0.f);

    float4 accA = fz, accB = fz, vsA = fz, vsB = fz;
    float denom = 0.f;
    const float posbase = (float)(quarter * 128);

    for (int it = 0; it < 4; ++it) {
        const int base = wv * 16 + 4 * it;
        int rr[4];
#pragma unroll
        for (int k = 0; k < 4; ++k) rr[k] = toksS[base + k] * 75;
        float4 A[4], Bv[4];
#pragma unroll
        for (int k = 0; k < 4; ++k) A[k] = emb4[rr[k] + lane];
#pragma unroll
        for (int k = 0; k < 4; ++k) Bv[k] = hasB ? emb4[rr[k] + 64 + lane] : fz;

        float pd[4];
#pragma unroll
        for (int k = 0; k < 4; ++k)
            pd[k] = A[k].x*kva.x + A[k].y*kva.y + A[k].z*kva.z + A[k].w*kva.w
                  + Bv[k].x*kvb.x + Bv[k].y*kvb.y + Bv[k].z*kvb.z + Bv[k].w*kvb.w;
#pragma unroll
        for (int off = 32; off > 0; off >>= 1) {
#pragma unroll
            for (int k = 0; k < 4; ++k) pd[k] += __shfl_xor(pd[k], off);
        }

#pragma unroll
        for (int k = 0; k < 4; ++k) {
            const float f = posbase + (float)(base + k);
            float lv = (f < startf) ? (startf - f) : ((f <= endf) ? 0.f : (f - endf));
            float wgt = 1.f - lv * inv_ml;
            wgt = (f < mem_len_f) ? wgt : 0.f;
            const float p = __expf(ftanh(wgt * pd[k] + qb));
            const float pw = p * wgt;
            accA.x += pw * A[k].x;  accA.y += pw * A[k].y;
            accA.z += pw * A[k].z;  accA.w += pw * A[k].w;
            accB.x += pw * Bv[k].x; accB.y += pw * Bv[k].y;
            accB.z += pw * Bv[k].z; accB.w += pw * Bv[k].w;
            vsA.x += A[k].x;  vsA.y += A[k].y;  vsA.z += A[k].z;  vsA.w += A[k].w;
            vsB.x += Bv[k].x; vsB.y += Bv[k].y; vsB.z += Bv[k].z; vsB.w += Bv[k].w;
            denom += p;
        }
    }

    *(float4*)&accW[wv * 300 + 4 * lane] = accA;
    *(float4*)&vsW [wv * 300 + 4 * lane] = vsA;
    if (hasB) {
        *(float4*)&accW[wv * 300 + 256 + 4 * lane] = accB;
        *(float4*)&vsW [wv * 300 + 256 + 4 * lane] = vsB;
    }
    if (lane == 0) denomW[wv] = denom;
    __syncthreads();

    if (t < 300) {
        float ds = 0.f;
#pragma unroll
        for (int w = 0; w < 8; ++w) ds += denomW[w];
        float ms = 0.f, vs = 0.f;
#pragma unroll
        for (int w = 0; w < 8; ++w) { ms += accW[w * 300 + t]; vs += vsW[w * 300 + t]; }
        ws[WS_ACC + bid * 300 + t] = ms;
        ws[WS_VSP + bid * 300 + t] = vs;
        if (t == 0) { ws[WS_SCAL + bid * 2] = ds; ws[WS_SCAL + bid * 2 + 1] = mem_len_f; }
    }
}

// ---------------------------------------------------------------------------
// k_tail: grid 256 x 960. Merge quarter-partials + 3 chained GEMVs + softmax.
// ---------------------------------------------------------------------------
__global__ __launch_bounds__(960) void k_tail(
    const float* __restrict__ Wk, const float* __restrict__ bk,
    const float* __restrict__ Wproj, const float* __restrict__ bproj,
    const float* __restrict__ Wm, const float* __restrict__ bm,
    const float* __restrict__ Wd, const float* __restrict__ bd,
    float* __restrict__ out, const float* __restrict__ ws)
{
    const int t = threadIdx.x;
    const int b = blockIdx.x;
    const int seg = t / 320, j = t - seg * 320;

    __shared__ float A[300], T[300], VSs[300], part[900], vms[300], lg[3];

    if (t < 300) {
        const int p0 = (b * 4) * 300 + t;
        float a = ws[WS_ACC + p0] + ws[WS_ACC + p0 + 300]
                + ws[WS_ACC + p0 + 600] + ws[WS_ACC + p0 + 900];
        float v = ws[WS_VSP + p0] + ws[WS_VSP + p0 + 300]
                + ws[WS_VSP + p0 + 600] + ws[WS_VSP + p0 + 900];
        const int s0 = b * 8;
        float d  = ws[WS_SCAL + s0] + ws[WS_SCAL + s0 + 2]
                 + ws[WS_SCAL + s0 + 4] + ws[WS_SCAL + s0 + 6];
        float ml = ws[WS_SCAL + s0 + 1];
        A[t]   = a / d;
        VSs[t] = v / ml;
    }
    __syncthreads();

    if (j < 300) {
        const int k0 = seg * 100;
        float acc = 0.f;
#pragma unroll 10
        for (int i = 0; i < 100; ++i) acc += A[k0 + i] * Wk[(k0 + i) * 300 + j];
        part[seg * 300 + j] = acc;
    }
    __syncthreads();
    if (t < 300) T[t] = part[t] + part[300 + t] + part[600 + t] + bk[t];
    __syncthreads();

    if (j < 300) {
        const int k0 = seg * 100;
        float acc = 0.f;
#pragma unroll 10
        for (int i = 0; i < 100; ++i) acc += T[k0 + i] * Wproj[(k0 + i) * 300 + j];
        part[seg * 300 + j] = acc;
    }
    __syncthreads();
    if (t < 300) A[t] = part[t] + part[300 + t] + part[600 + t] + bproj[t] + VSs[t];
    __syncthreads();

    if (j < 300) {
        const int k0 = seg * 100;
        float acc = 0.f;
#pragma unroll 10
        for (int i = 0; i < 100; ++i) acc += A[k0 + i] * Wm[(k0 + i) * 300 + j];
        part[seg * 300 + j] = acc;
    }
    __syncthreads();
    if (t < 300) vms[t] = tanhf(part[t] + part[300 + t] + part[600 + t] + bm[t]);
    __syncthreads();

    const int wv = t >> 6, lane = t & 63;
    if (wv < 3) {
        float p = 0.f;
#pragma unroll
        for (int k = 0; k < 5; ++k) { int d = lane + 64 * k; if (d < 300) p += vms[d] * Wd[d * 3 + wv]; }
        p = wred(p);
        if (lane == 0) lg[wv] = p + bd[wv];
    }
    __syncthreads();
    if (t == 0) {
        float l0 = lg[0], l1 = lg[1], l2 = lg[2];
        float mx = fmaxf(l0, fmaxf(l1, l2));
        float e0 = expf(l0 - mx), e1 = expf(l1 - mx), e2 = expf(l2 - mx);
        float s = e0 + e1 + e2;
        out[b * 3 + 0] = e0 / s;
        out[b * 3 + 1] = e1 / s;
        out[b * 3 + 2] = e2 / s;
    }
}

extern "C" void kernel_launch(void* const* d_in, const int* in_sizes, int n_in,
                              void* d_out, int out_size, void* d_ws, size_t ws_size,
                              hipStream_t stream)
{
    (void)in_sizes; (void)n_in; (void)out_size; (void)ws_size;
    const int*   text   = (const int*)d_in[0];
    const int*   aspect = (const int*)d_in[1];
    const int*   left   = (const int*)d_in[2];
    const float* embed  = (const float*)d_in[3];
    const float* Wx     = (const float*)d_in[4];
    // d_in[5] = Ws : dead code in reference
    const float* Wk     = (const float*)d_in[6];
    const float* bk     = (const float*)d_in[7];
    const float* Wq     = (const float*)d_in[8];
    const float* bq     = (const float*)d_in[9];
    const float* wmlp   = (const float*)d_in[10];
    const float* Wproj  = (const float*)d_in[11];
    const float* bproj  = (const float*)d_in[12];
    const float* Wm     = (const float*)d_in[13];
    const float* bm     = (const float*)d_in[14];
    const float* Wd     = (const float*)d_in[15];
    const float* bd     = (const float*)d_in[16];
    float* out = (float*)d_out;
    float* ws  = (float*)d_ws;

    hipLaunchKernelGGL(k_prep, dim3(302), dim3(64), 0, stream, Wk, bk, Wq, bq, wmlp, ws);
    hipLaunchKernelGGL(k_hop, dim3(300), dim3(64), 0, stream, Wx, ws + WS_H0, ws + WS_H1);
    hipLaunchKernelGGL(k_hop, dim3(300), dim3(64), 0, stream, Wx, ws + WS_H1, ws + WS_H0);
    hipLaunchKernelGGL(k_hop, dim3(300), dim3(64), 0, stream, Wx, ws + WS_H0, ws + WS_H1);
    hipLaunchKernelGGL(k_row, dim3(256), dim3(512), 0, stream, text, aspect, left, embed, ws);
    hipLaunchKernelGGL(k_main, dim3(1024), dim3(512), 0, stream, text, embed, ws);
    hipLaunchKernelGGL(k_tail, dim3(256), dim3(960), 0, stream,
                       Wk, bk, Wproj, bproj, Wm, bm, Wd, bd, out, ws);
}